// Round 1
// 74.906 us; speedup vs baseline: 1.0161x; 1.0161x over previous
//
#include <hip/hip_runtime.h>
#include <math.h>

#define NQ 4
#define NL 2
#define PAIRS 2   // float2-packed batch-element pairs per thread (4 elems/thread)

// <2 x float> so the backend can form v_pk_mul_f32 / v_pk_fma_f32 (packed fp32,
// 2 FMA/lane/cycle — the only path to the 157 TF fp32 peak on gfx950).
typedef float v2f __attribute__((ext_vector_type(2)));

static __device__ __forceinline__ v2f splat(float a) { return (v2f){a, a}; }

// One thread = 2*PAIRS batch elements, processed as PAIRS float2 streams.
// Index convention: k = b0*8 + b1*4 + b2*2 + b3 (wire 0 = MSB), matching the
// reference's [2,2,2,2] flatten and its z-sign table. Weight half-angle trig
// computed once per thread (batch-uniform), amortized over 4 elements.
__global__ __launch_bounds__(256) void qsim_kernel(
        const float4* __restrict__ x,      // [B] of float4 (x[:,0..3])
        const float*  __restrict__ w,      // [NL*NQ] weights
        float4* __restrict__ out,          // [B] of float4 (out[:,0..3])
        int B) {
    const int tid   = blockIdx.x * blockDim.x + threadIdx.x;
    const int total = gridDim.x * blockDim.x;   // grid stride

    // Batch-uniform weight trig — once per thread (scalar regs, splatted at use;
    // pk ops can read the same VGPR for both halves via op_sel).
    float wc[NL * NQ], wsn[NL * NQ];
#pragma unroll
    for (int i = 0; i < NL * NQ; ++i) {
        __sincosf(0.5f * w[i], &wsn[i], &wc[i]);
    }

    // Hoist ALL global loads: 4 dwordx4 in flight before any compute (MLP).
    float4 xv[2 * PAIRS];
#pragma unroll
    for (int e = 0; e < 2 * PAIRS; ++e) {
        const int b = tid + e * total;           // coalesced per iteration
        xv[e] = (b < B) ? x[b] : make_float4(0.f, 0.f, 0.f, 0.f);
    }

#pragma unroll
    for (int pr = 0; pr < PAIRS; ++pr) {
        const float4 xa = xv[2 * pr];            // element A of the pair
        const float4 xb = xv[2 * pr + 1];        // element B of the pair

        // Data-encoding trig (scalar: v_sin/v_cos are scalar-only), then pack.
        float sA0, cA0, sA1, cA1, sA2, cA2, sA3, cA3;
        float sB0, cB0, sB1, cB1, sB2, cB2, sB3, cB3;
        __sincosf(0.5f * xa.x, &sA0, &cA0);
        __sincosf(0.5f * xa.y, &sA1, &cA1);
        __sincosf(0.5f * xa.z, &sA2, &cA2);
        __sincosf(0.5f * xa.w, &sA3, &cA3);
        __sincosf(0.5f * xb.x, &sB0, &cB0);
        __sincosf(0.5f * xb.y, &sB1, &cB1);
        __sincosf(0.5f * xb.z, &sB2, &cB2);
        __sincosf(0.5f * xb.w, &sB3, &cB3);

        const v2f c0 = (v2f){cA0, cB0}, s0 = (v2f){sA0, sB0};
        const v2f c1 = (v2f){cA1, cB1}, s1 = (v2f){sA1, sB1};
        const v2f c2 = (v2f){cA2, cB2}, s2 = (v2f){sA2, sB2};
        const v2f c3 = (v2f){cA3, cB3}, s3 = (v2f){sA3, sB3};

        // Product state |0..0> after the 4 encoding RYs — all packed muls.
        const v2f a00 = c0 * c1, a01 = c0 * s1, a10 = s0 * c1, a11 = s0 * s1;
        const v2f g00 = c2 * c3, g01 = c2 * s3, g10 = s2 * c3, g11 = s2 * s3;

        v2f st[16];
        st[ 0] = a00 * g00; st[ 1] = a00 * g01; st[ 2] = a00 * g10; st[ 3] = a00 * g11;
        st[ 4] = a01 * g00; st[ 5] = a01 * g01; st[ 6] = a01 * g10; st[ 7] = a01 * g11;
        st[ 8] = a10 * g00; st[ 9] = a10 * g01; st[10] = a10 * g10; st[11] = a10 * g11;
        st[12] = a11 * g00; st[13] = a11 * g01; st[14] = a11 * g10; st[15] = a11 * g11;

        // Variational layers: RY(weights[l][q]) per wire, then CNOT chain.
        // Every butterfly is componentwise on the element-pair → pk_mul/pk_fma.
#pragma unroll
        for (int l = 0; l < NL; ++l) {
#pragma unroll
            for (int q = 0; q < NQ; ++q) {
                const v2f c = splat(wc[l * NQ + q]);
                const v2f s = splat(wsn[l * NQ + q]);
                const int str = 8 >> q;
#pragma unroll
                for (int k = 0; k < 16; ++k) {
                    if ((k & str) == 0) {
                        const v2f u = st[k], v = st[k + str];
                        st[k]       = c * u - s * v;
                        st[k + str] = s * u + c * v;
                    }
                }
            }
            // CNOT(ctrl=q, tgt=q+1): compile-time register permutation — free.
#pragma unroll
            for (int q = 0; q < NQ - 1; ++q) {
                const int cs = 8 >> q;
                const int ts = 8 >> (q + 1);
#pragma unroll
                for (int k = 0; k < 16; ++k) {
                    if ((k & cs) != 0 && (k & ts) == 0) {
                        const v2f t = st[k];
                        st[k] = st[k + ts];
                        st[k + ts] = t;
                    }
                }
            }
        }

        // probs + signed sums (all packed).
        v2f p[16];
#pragma unroll
        for (int k = 0; k < 16; ++k) p[k] = st[k] * st[k];

        v2f q2[8];
        v2f o3 = splat(0.f);
#pragma unroll
        for (int i = 0; i < 8; ++i) {
            q2[i] = p[2 * i] + p[2 * i + 1];
            o3   += p[2 * i] - p[2 * i + 1];
        }
        v2f r4[4];
        v2f o2 = splat(0.f);
#pragma unroll
        for (int i = 0; i < 4; ++i) {
            r4[i] = q2[2 * i] + q2[2 * i + 1];
            o2   += q2[2 * i] - q2[2 * i + 1];
        }
        const v2f o1 = (r4[0] - r4[1]) + (r4[2] - r4[3]);
        const v2f o0 = (r4[0] + r4[1]) - (r4[2] + r4[3]);

        // Unpack (free: .x/.y are just the two VGPRs of the pair) and store.
        const int b0 = tid + (2 * pr) * total;
        const int b1 = tid + (2 * pr + 1) * total;
        if (b0 < B) out[b0] = make_float4(o0.x, o1.x, o2.x, o3.x);
        if (b1 < B) out[b1] = make_float4(o0.y, o1.y, o2.y, o3.y);
    }
}

extern "C" void kernel_launch(void* const* d_in, const int* in_sizes, int n_in,
                              void* d_out, int out_size, void* d_ws, size_t ws_size,
                              hipStream_t stream) {
    const float* x = (const float*)d_in[0];        // [B,4]
    const float* w = (const float*)d_in[1];        // [2,4]
    float* out = (float*)d_out;                    // [B,4]

    int B = in_sizes[0] / 4;

    int block = 256;
    int per_block = block * 2 * PAIRS;             // 4 elements per thread
    int grid = (B + per_block - 1) / per_block;
    qsim_kernel<<<grid, block, 0, stream>>>(
        (const float4*)x, w, (float4*)out, B);
}